// Round 9
// baseline (275.207 us; speedup 1.0000x reference)
//
#include <hip/hip_runtime.h>
#include <hip/hip_bf16.h>

#define N_SEQ 2048
#define DSTR 1024
#define NH 32          // B*HEADS
#define QKVN 3072      // HEADS*D_HEAD
#define MROWS 4096     // N*B
#define LOG2E 1.4426950408889634f

typedef float f32x4 __attribute__((ext_vector_type(4)));
typedef short bf16x8 __attribute__((ext_vector_type(8)));
typedef short short4v __attribute__((ext_vector_type(4)));
typedef unsigned short ushort4v __attribute__((ext_vector_type(4)));
typedef unsigned short u16t;

__device__ __forceinline__ u16t f2bf(float f) {
  union { float f; unsigned u; } x; x.f = f;
  return (u16t)((x.u + 0x7fff + ((x.u >> 16) & 1)) >> 16);
}
__device__ __forceinline__ float bf2f(u16t u) {
  union { unsigned u; float f; } x; x.u = ((unsigned)u) << 16; return x.f;
}
// packs bf16(a) into low 16, bf16(b) into high 16 (RNE)
__device__ __forceinline__ unsigned cvt_pk_bf16(float a, float b) {
  unsigned r;
  asm("v_cvt_pk_bf16_f32 %0, %1, %2" : "=v"(r) : "v"(a), "v"(b));
  return r;
}
// 2^x via v_exp_f32 (pure, schedulable)
__device__ __forceinline__ float exp2a(float x) {
  float r;
  asm("v_exp_f32 %0, %1" : "=v"(r) : "v"(x));
  return r;
}

#define MFMA16(a, b, c) __builtin_amdgcn_mfma_f32_16x16x32_bf16(a, b, c, 0, 0, 0)

__device__ __forceinline__ void gl2lds16(const void* g, void* l) {
  __builtin_amdgcn_global_load_lds((const __attribute__((address_space(1))) void*)g,
                                   (__attribute__((address_space(3))) void*)l, 16, 0, 0);
}

// ---------------- elementwise fp32*scale -> bf16 hi (+ optional lo), vectorized x4
__global__ void split_f32_kernel(const float* __restrict__ in, u16t* __restrict__ hi,
                                 u16t* __restrict__ lo, int n4, float scale) {
  int i = blockIdx.x * blockDim.x + threadIdx.x;
  if (i >= n4) return;
  float4 v = ((const float4*)in)[i];
  float vv[4] = {v.x * scale, v.y * scale, v.z * scale, v.w * scale};
  ushort4v h, l;
  #pragma unroll
  for (int j = 0; j < 4; j++) {
    h[j] = f2bf(vv[j]);
    l[j] = f2bf(vv[j] - bf2f(h[j]));
  }
  ((ushort4v*)hi)[i] = h;
  if (lo) ((ushort4v*)lo)[i] = l;
}

// ---------------- transpose: in fp32 [K][Nc] -> bf16 [Nc][K]
__global__ void transpose_split_kernel(const float* __restrict__ in,
                                       u16t* __restrict__ hi, u16t* __restrict__ lo,
                                       int K, int Nc) {
  __shared__ float tile[32][33];
  const int n0 = blockIdx.x * 32, k0 = blockIdx.y * 32;
  const int tx = threadIdx.x, ty = threadIdx.y;
  #pragma unroll
  for (int j = 0; j < 32; j += 8)
    tile[ty + j][tx] = in[(size_t)(k0 + ty + j) * Nc + n0 + tx];
  __syncthreads();
  #pragma unroll
  for (int j = 0; j < 32; j += 8) {
    float v = tile[tx][ty + j];
    size_t o = (size_t)(n0 + ty + j) * K + k0 + tx;
    u16t h = f2bf(v);
    hi[o] = h;
    if (lo) lo[o] = f2bf(v - bf2f(h));
  }
}

// ---------------- GEMM 1: qkv = stream @ w_qkv + b_qkv
// A split hi/lo (2 MFMA streams), B hi only. Q pre-scaled by log2e for exp2 softmax.
__global__ __launch_bounds__(256, 3) void gemm_qkv_kernel(
    const u16t* __restrict__ Ahi, const u16t* __restrict__ Alo,
    const u16t* __restrict__ Bhi, const float* __restrict__ bias,
    u16t* __restrict__ Qhi, u16t* __restrict__ Qlo,
    u16t* __restrict__ Khi, u16t* __restrict__ Vt) {
  constexpr int BK = 64;
  __shared__ u16t sAh[128 * 64], sAl[128 * 64], sBh[128 * 64];
  const int t = threadIdx.x;
  const int lane = t & 63, wid = t >> 6;
  const int wm = wid >> 1, wn = wid & 1;
  const int g = lane >> 4, cc = lane & 15;
  const int m0 = blockIdx.x * 128, n0 = blockIdx.y * 128;
  const int srow = t >> 3;                           // 0..31 (+32 per iter)
  const int sc = ((t & 7) ^ ((t >> 3) & 7)) * 8;     // swizzled source chunk (u16)

  f32x4 acc[4][4] = {};

  for (int k0 = 0; k0 < DSTR; k0 += BK) {
    __syncthreads();
    #pragma unroll
    for (int i = 0; i < 4; i++) {
      const int row = i * 32 + srow;
      gl2lds16(Ahi + (size_t)(m0 + row) * DSTR + k0 + sc, &sAh[i * 2048 + wid * 512]);
      gl2lds16(Alo + (size_t)(m0 + row) * DSTR + k0 + sc, &sAl[i * 2048 + wid * 512]);
      gl2lds16(Bhi + (size_t)(n0 + row) * DSTR + k0 + sc, &sBh[i * 2048 + wid * 512]);
    }
    __syncthreads();
    #pragma unroll
    for (int kk = 0; kk < 2; kk++) {
      bf16x8 ah[4], al[4], bh[4];
      #pragma unroll
      for (int mt = 0; mt < 4; mt++) {
        const int r = wm * 64 + mt * 16 + cc;
        const int c = ((4 * kk + g) ^ (cc & 7)) * 8;
        ah[mt] = *(const bf16x8*)&sAh[r * 64 + c];
        al[mt] = *(const bf16x8*)&sAl[r * 64 + c];
      }
      #pragma unroll
      for (int nt = 0; nt < 4; nt++) {
        const int r = wn * 64 + nt * 16 + cc;
        const int c = ((4 * kk + g) ^ (cc & 7)) * 8;
        bh[nt] = *(const bf16x8*)&sBh[r * 64 + c];
      }
      #pragma unroll
      for (int mt = 0; mt < 4; mt++)
        #pragma unroll
        for (int nt = 0; nt < 4; nt++) {
          acc[mt][nt] = MFMA16(ah[mt], bh[nt], acc[mt][nt]);
          acc[mt][nt] = MFMA16(al[mt], bh[nt], acc[mt][nt]);
        }
    }
  }
  // epilogue: bias, scatter to Qhi/Qlo (log2e-scaled), Khi, plain Vt
  #pragma unroll
  for (int mt = 0; mt < 4; mt++)
    #pragma unroll
    for (int nt = 0; nt < 4; nt++)
      #pragma unroll
      for (int r = 0; r < 4; r++) {
        int grow = m0 + wm * 64 + mt * 16 + g * 4 + r;
        int gcol = n0 + wn * 64 + nt * 16 + cc;
        float val = acc[mt][nt][r] + bias[gcol];
        int nn = grow >> 1, bb = grow & 1;
        int hl = gcol / 192, off = gcol - hl * 192;
        int hh = bb * 16 + hl;
        if (off < 64) {
          val *= LOG2E;  // softmax runs in exp2 domain
          size_t o = ((size_t)hh * N_SEQ + nn) * 64 + off;
          u16t h_ = f2bf(val);
          Qhi[o] = h_;
          Qlo[o] = f2bf(val - bf2f(h_));
        } else if (off < 128) {
          Khi[((size_t)hh * N_SEQ + nn) * 64 + (off - 64)] = f2bf(val);
        } else {
          Vt[((size_t)hh * 64 + (off - 128)) * N_SEQ + nn] = f2bf(val);
        }
      }
}

// ---------------- flash attention: swapped QK^T (lane owns one q), 8 waves,
// QBLK=128, KVBLK=64, dbuf LDS K/V, exp2-domain softmax, defer-max,
// XOR-swizzled per-wave sP (chunk-aligned bijective b64 store).
__global__ __launch_bounds__(512, 4) void attn_kernel(
    const u16t* __restrict__ Qhi, const u16t* __restrict__ Qlo,
    const u16t* __restrict__ Khi, const u16t* __restrict__ Vt,
    const u16t* __restrict__ maskb, u16t* __restrict__ Vals) {
  __shared__ u16t sKh[2][64 * 64];
  __shared__ u16t sV[2][64 * 64];
  __shared__ u16t sP[8][16 * 64];
  const int t = threadIdx.x;
  const int lane = t & 63, wid = t >> 6;
  const int g = lane >> 4, cc = lane & 15;
  const int h = blockIdx.x >> 4;
  const int qt = blockIdx.x & 15;
  const int q0 = qt * 128 + wid * 16;

  const size_t kbase = (size_t)h * N_SEQ * 64;
  const size_t vbase = (size_t)h * 64 * N_SEQ;

  const int srow = t >> 3;                        // 0..63 (512 threads)
  const int sc = ((t & 7) ^ ((t >> 3) & 7)) * 8;  // inverse-swizzled source chunk

  auto stage = [&](int buf, int mt0) {
    gl2lds16(Khi + kbase + (size_t)(mt0 + srow) * 64 + sc, &sKh[buf][wid * 512]);
    gl2lds16(Vt + vbase + (size_t)srow * N_SEQ + mt0 + sc, &sV[buf][wid * 512]);
  };

  const size_t qoff = kbase + (size_t)(q0 + cc) * 64 + g * 8;
  bf16x8 qh0 = *(const bf16x8*)(Qhi + qoff);
  bf16x8 qh1 = *(const bf16x8*)(Qhi + qoff + 32);
  bf16x8 ql0 = *(const bf16x8*)(Qlo + qoff);
  bf16x8 ql1 = *(const bf16x8*)(Qlo + qoff + 32);

  f32x4 o[4] = {};
  float M = -1e30f, L = 0.0f;   // per-lane: q = q0 + cc (log2 domain)

  stage(0, 0);
  int cur = 0;
  const int sw = (cc & 7) * 8;
  u16t* sPw = sP[wid];
  const int alane = (lane & 48) + g * 4;  // base src lane for row-state gathers

  for (int ti = 0; ti < N_SEQ / 64; ++ti) {
    const int mt0 = ti * 64;
    __syncthreads();  // staging of buf[cur] complete; all waves off buf[cur^1]
    if (ti + 1 < N_SEQ / 64) stage(cur ^ 1, mt0 + 64);

    // mask in natural [q][k] layout: 4 x b64, rows = this lane's q
    ushort4v ml[4];
    #pragma unroll
    for (int mt = 0; mt < 4; ++mt)
      ml[mt] = *(const ushort4v*)&maskb[(size_t)(q0 + cc) * N_SEQ + mt0 + mt * 16 + g * 4];

    // swapped QK^T: D[key][q] -> lane holds 16 key-scores for q = q0+cc
    f32x4 s[4];
    #pragma unroll
    for (int mt = 0; mt < 4; ++mt) {
      const int krow = (mt * 16 + cc) * 64;
      bf16x8 kh0 = *(const bf16x8*)&sKh[cur][krow + ((g * 8) ^ sw)];
      bf16x8 kh1 = *(const bf16x8*)&sKh[cur][krow + ((32 + g * 8) ^ sw)];
      f32x4 a = {};
      a = MFMA16(kh0, qh0, a);
      a = MFMA16(kh1, qh1, a);
      a = MFMA16(kh0, ql0, a);
      a = MFMA16(kh1, ql1, a);
      s[mt] = a;
    }
    // mask add + in-lane max (16 values), then 2 cross-g shuffles
    float pm = -1e30f;
    #pragma unroll
    for (int mt = 0; mt < 4; ++mt)
      #pragma unroll
      for (int r = 0; r < 4; ++r) {
        s[mt][r] += bf2f(ml[mt][r]);
        pm = fmaxf(pm, s[mt][r]);
      }
    pm = fmaxf(pm, __shfl_xor(pm, 16));
    pm = fmaxf(pm, __shfl_xor(pm, 32));

    if (__any(pm - M > 11.54f)) {  // defer-max (log2 units)
      float nM = fmaxf(M, pm);
      float alpha = exp2a(M - nM);
      L *= alpha;
      M = nM;
      float ar[4];
      #pragma unroll
      for (int r = 0; r < 4; ++r) ar[r] = __shfl(alpha, alane + r);
      #pragma unroll
      for (int dt = 0; dt < 4; ++dt)
        #pragma unroll
        for (int r = 0; r < 4; ++r) o[dt][r] *= ar[r];
    }

    float p[4][4];
    float rs = 0.0f;
    #pragma unroll
    for (int mt = 0; mt < 4; ++mt)
      #pragma unroll
      for (int r = 0; r < 4; ++r) {
        p[mt][r] = exp2a(s[mt][r] - M);
        rs += p[mt][r];
      }
    rs += __shfl_xor(rs, 16);
    rs += __shfl_xor(rs, 32);
    L += rs;

    // P store: element k = mt*16 + g*4 + r lands at ((k&~7)^sw) + (k&7).
    // Single b64 store of short4 (same TBAA class as the bf16x8/short8 read).
    #pragma unroll
    for (int mt = 0; mt < 4; ++mt) {
      unsigned w0 = cvt_pk_bf16(p[mt][0], p[mt][1]);
      unsigned w1 = cvt_pk_bf16(p[mt][2], p[mt][3]);
      const int kb = mt * 16 + (g >> 1) * 8;
      short4v pv;
      pv[0] = (short)w0; pv[1] = (short)(w0 >> 16);
      pv[2] = (short)w1; pv[3] = (short)(w1 >> 16);
      *(short4v*)&sPw[cc * 64 + (kb ^ sw) + (g & 1) * 4] = pv;
    }
    bf16x8 pf0 = *(const bf16x8*)&sPw[cc * 64 + ((g * 8) ^ sw)];
    bf16x8 pf1 = *(const bf16x8*)&sPw[cc * 64 + ((32 + g * 8) ^ sw)];
    #pragma unroll
    for (int dt = 0; dt < 4; ++dt) {
      const int vrow = (dt * 16 + cc) * 64;
      bf16x8 v0 = *(const bf16x8*)&sV[cur][vrow + ((g * 8) ^ sw)];
      bf16x8 v1 = *(const bf16x8*)&sV[cur][vrow + ((32 + g * 8) ^ sw)];
      o[dt] = MFMA16(pf0, v0, o[dt]);
      o[dt] = MFMA16(pf1, v1, o[dt]);
    }
    cur ^= 1;
  }
  float invL = 1.0f / L;
  float ir[4];
  #pragma unroll
  for (int r = 0; r < 4; ++r) ir[r] = __shfl(invL, alane + r);
  const int bb = h >> 4, hl = h & 15;
  #pragma unroll
  for (int r = 0; r < 4; ++r) {
    const int q = q0 + g * 4 + r;
    const size_t orow = (size_t)(q * 2 + bb) * DSTR + hl * 64;
    #pragma unroll
    for (int dt = 0; dt < 4; ++dt)
      Vals[orow + dt * 16 + cc] = f2bf(o[dt][r] * ir[r]);
  }
}

// ---------------- GEMM 3: out = Vals @ w_out + b_out (plain bf16, m97-style)
__global__ __launch_bounds__(256, 3) void gemm_out_kernel(
    const u16t* __restrict__ A, const u16t* __restrict__ Bt,
    const float* __restrict__ bias, float* __restrict__ out) {
  constexpr int BK = 64;
  __shared__ u16t sA[128 * 64], sB[128 * 64];
  const int t = threadIdx.x;
  const int lane = t & 63, wid = t >> 6;
  const int wm = wid >> 1, wn = wid & 1;
  const int g = lane >> 4, cc = lane & 15;
  const int m0 = blockIdx.x * 128, n0 = blockIdx.y * 128;
  const int srow = t >> 3;
  const int sc = ((t & 7) ^ ((t >> 3) & 7)) * 8;

  f32x4 acc[4][4] = {};
  for (int k0 = 0; k0 < DSTR; k0 += BK) {
    __syncthreads();
    #pragma unroll
    for (int i = 0; i < 4; i++) {
      const int row = i * 32 + srow;
      gl2lds16(A + (size_t)(m0 + row) * DSTR + k0 + sc, &sA[i * 2048 + wid * 512]);
      gl2lds16(Bt + (size_t)(n0 + row) * DSTR + k0 + sc, &sB[i * 2048 + wid * 512]);
    }
    __syncthreads();
    #pragma unroll
    for (int kk = 0; kk < 2; kk++) {
      bf16x8 af[4], bfr[4];
      #pragma unroll
      for (int mt = 0; mt < 4; mt++) {
        const int r = wm * 64 + mt * 16 + cc;
        const int c = ((4 * kk + g) ^ (cc & 7)) * 8;
        af[mt] = *(const bf16x8*)&sA[r * 64 + c];
      }
      #pragma unroll
      for (int nt = 0; nt < 4; nt++) {
        const int r = wn * 64 + nt * 16 + cc;
        const int c = ((4 * kk + g) ^ (cc & 7)) * 8;
        bfr[nt] = *(const bf16x8*)&sB[r * 64 + c];
      }
      #pragma unroll
      for (int mt = 0; mt < 4; mt++)
        #pragma unroll
        for (int nt = 0; nt < 4; nt++)
          acc[mt][nt] = MFMA16(af[mt], bfr[nt], acc[mt][nt]);
    }
  }
  #pragma unroll
  for (int mt = 0; mt < 4; mt++)
    #pragma unroll
    for (int nt = 0; nt < 4; nt++)
      #pragma unroll
      for (int r = 0; r < 4; r++) {
        int grow = m0 + wm * 64 + mt * 16 + g * 4 + r;
        int gcol = n0 + wn * 64 + nt * 16 + cc;
        out[(size_t)grow * DSTR + gcol] = acc[mt][nt][r] + bias[gcol];
      }
}

extern "C" void kernel_launch(void* const* d_in, const int* in_sizes, int n_in,
                              void* d_out, int out_size, void* d_ws, size_t ws_size,
                              hipStream_t stream) {
  (void)in_sizes; (void)n_in; (void)out_size; (void)ws_size;
  const float* x      = (const float*)d_in[0];
  const float* mask   = (const float*)d_in[1];
  const float* w_qkv  = (const float*)d_in[2];
  const float* b_qkv  = (const float*)d_in[3];
  const float* w_out  = (const float*)d_in[4];
  const float* b_out  = (const float*)d_in[5];
  float* out = (float*)d_out;

  char* ws = (char*)d_ws;
  size_t off = 0;
  auto alloc = [&](size_t n) { void* p = ws + off; off += (n + 255) & ~(size_t)255; return p; };
  u16t* WqkvT = (u16t*)alloc((size_t)QKVN * DSTR * 2);
  u16t* WoutT = (u16t*)alloc((size_t)DSTR * DSTR * 2);
  u16t* Qhi = (u16t*)alloc((size_t)NH * N_SEQ * 64 * 2);
  u16t* Qlo = (u16t*)alloc((size_t)NH * N_SEQ * 64 * 2);
  u16t* Khi = (u16t*)alloc((size_t)NH * N_SEQ * 64 * 2);
  u16t* Vt  = (u16t*)alloc((size_t)NH * 64 * N_SEQ * 2);
  u16t* Xhi = (u16t*)alloc((size_t)MROWS * DSTR * 2);  // reused as Vals after gemm_qkv
  u16t* Xlo = (u16t*)alloc((size_t)MROWS * DSTR * 2);
  u16t* MaskB = (u16t*)alloc((size_t)N_SEQ * N_SEQ * 2);
  u16t* Vals = Xhi;  // alias: X consumed by gemm_qkv before attn writes Vals

  split_f32_kernel<<<dim3(MROWS * DSTR / 4 / 256), 256, 0, stream>>>(
      x, Xhi, Xlo, MROWS * DSTR / 4, 1.0f);
  split_f32_kernel<<<dim3(N_SEQ * N_SEQ / 4 / 256), 256, 0, stream>>>(
      mask, MaskB, nullptr, N_SEQ * N_SEQ / 4, LOG2E);
  transpose_split_kernel<<<dim3(QKVN / 32, DSTR / 32), dim3(32, 8), 0, stream>>>(
      w_qkv, WqkvT, nullptr, DSTR, QKVN);
  transpose_split_kernel<<<dim3(DSTR / 32, DSTR / 32), dim3(32, 8), 0, stream>>>(
      w_out, WoutT, nullptr, DSTR, DSTR);
  gemm_qkv_kernel<<<dim3(MROWS / 128, QKVN / 128), 256, 0, stream>>>(
      Xhi, Xlo, WqkvT, b_qkv, Qhi, Qlo, Khi, Vt);
  attn_kernel<<<dim3(NH * (N_SEQ / 128)), 512, 0, stream>>>(
      Qhi, Qlo, Khi, Vt, MaskB, Vals);
  gemm_out_kernel<<<dim3(MROWS / 128, DSTR / 128), 256, 0, stream>>>(
      Vals, WoutT, b_out, out);
}